// Round 7
// baseline (560.745 us; speedup 1.0000x reference)
//
#include <hip/hip_runtime.h>

// ChildSumTreeLSTM on a static 4-ary heap tree.
// N=8192, H=256, D=300, K=4, OUT=4. Leaves = 2048..8191. Internal 0..2047 in 7 levels.
// Workspace: gx [8192][1024] f32, Hb [8192][256] f32, Cb [8192][256] f32.
// D (level scratch) aliases gx rows 2048.. (dead after leaf_kernel).
// Tail counters live in gx row 8191 cols 256.. (leaf f-cols: never written/read;
// zeroed by gx_gemm each replay -> safe under workspace re-poisoning).
//
// Structure (12 dispatches):
//   1. gx_gemm     — 128x128 tiles, 8x8 acc/thread, pipelined, XCD-swizzled
//                    (emb L2-resident), dead leaf-f tiles skipped, zeroes cnts.
//   2. leaf_kernel — 4 nodes/block.
//   3-8. big levels M=683,1024,256: level_gemm (64x64, pipelined) + level_pointwise.
//   9-12. tail levels M=64,16,4,1: tail_gemm = level_gemm body + LAST-BLOCK
//         fused pointwise (fence+atomic count; 28th block runs the level's
//         pointwise in-block; root block also emits logits/log_softmax).
//         Single sync point, no spinning — NOT the round-1 grid barrier.
// Rules (rounds 1-6): no grid barriers (~170us); no chunked fused-GEMV levels
// (round 6: 95us @ M=683, LDS-latency-chained at 2 blocks/CU); 64x64 pair is
// the proven level engine; launch tax ~14us/dispatch -> cut dispatches safely.

#define N_NODES 8192
#define HDIM 256
#define DDIM 300
#define GXC 1024
#define LEAF_FIRST 2048
#define WH_STRIDE 65536   // 256*256
#define TAIL_NBLK 28      // (1 col-tile) * 7 secs * 4 row-tiles

__device__ __forceinline__ float sigf(float x) { return 1.0f / (1.0f + __expf(-x)); }

// ---------- Kernel 1: gx[n][c] = emb[xs[n]] · Wx[c] + bx[c]  (128x128 tile) --
__global__ __launch_bounds__(256) void gx_gemm(
    const int* __restrict__ xs, const float* __restrict__ emb,
    const float* __restrict__ Wx, const float* __restrict__ bx,
    float* __restrict__ gx, unsigned* __restrict__ cnts)
{
    // Zero the tail-level last-block counters (runs before all level gemms).
    if (blockIdx.x == 0 && blockIdx.y == 0 && threadIdx.x == 0) {
        cnts[0] = 0u; cnts[1] = 0u; cnts[2] = 0u; cnts[3] = 0u;
    }

    // XCD remap: grid (8,64) -> lid 0..511; xcd = lid&7 owns row-tiles
    // 8*xcd..8*xcd+7 with all 8 col-tiles -> emb rows HBM-fetched once/XCD.
    const int lid  = blockIdx.x + blockIdx.y * gridDim.x;
    const int rowt = (lid & 7) * 8 + ((lid >> 3) & 7);   // 0..63
    const int colt = lid >> 6;                           // 0..7
    const int n0 = rowt * 128;
    const int c0 = colt * 128;
    // Leaf rows' f-gate cols (256..511 = col-tiles 2,3) never read: skip.
    if (n0 >= LEAF_FIRST && (colt == 2 || colt == 3)) return;

    __shared__ __align__(16) float As[16][132];
    __shared__ __align__(16) float Bs[16][132];
    const int tid  = threadIdx.x;
    const int sr   = tid >> 1;           // staging row 0..127
    const int sk8  = (tid & 1) << 3;     // staging k-offset 0/8
    const int trow = (tid >> 4) << 3;    // 0..120
    const int tcol = (tid & 15) << 3;    // 0..120

    const long arow = (long)xs[n0 + sr] * DDIM;
    const long brow = (long)(c0 + sr) * DDIM;

    float acc[8][8] = {};

    // prefetch chunk 0 (fully in-range: 16 <= 300)
    float4 a0 = *(const float4*)(emb + arow + sk8);
    float4 a1 = *(const float4*)(emb + arow + sk8 + 4);
    float4 b0 = *(const float4*)(Wx  + brow + sk8);
    float4 b1 = *(const float4*)(Wx  + brow + sk8 + 4);

    for (int k0 = 0; k0 < DDIM; k0 += 16) {
        __syncthreads();
        As[sk8+0][sr] = a0.x; As[sk8+1][sr] = a0.y; As[sk8+2][sr] = a0.z; As[sk8+3][sr] = a0.w;
        As[sk8+4][sr] = a1.x; As[sk8+5][sr] = a1.y; As[sk8+6][sr] = a1.z; As[sk8+7][sr] = a1.w;
        Bs[sk8+0][sr] = b0.x; Bs[sk8+1][sr] = b0.y; Bs[sk8+2][sr] = b0.z; Bs[sk8+3][sr] = b0.w;
        Bs[sk8+4][sr] = b1.x; Bs[sk8+5][sr] = b1.y; Bs[sk8+6][sr] = b1.z; Bs[sk8+7][sr] = b1.w;
        __syncthreads();

        // prefetch next chunk (overlaps compute); zero-pad past DDIM
        const int kn = k0 + 16;
        a0 = make_float4(0.f,0.f,0.f,0.f); a1 = a0; b0 = a0; b1 = a0;
        if (kn < DDIM) {
            if (kn + sk8 < DDIM) {
                a0 = *(const float4*)(emb + arow + kn + sk8);
                b0 = *(const float4*)(Wx  + brow + kn + sk8);
            }
            if (kn + sk8 + 4 < DDIM) {
                a1 = *(const float4*)(emb + arow + kn + sk8 + 4);
                b1 = *(const float4*)(Wx  + brow + kn + sk8 + 4);
            }
        }

        #pragma unroll
        for (int k = 0; k < 16; k++) {
            const float4 av0 = *(const float4*)&As[k][trow];
            const float4 av1 = *(const float4*)&As[k][trow + 4];
            const float4 bv0 = *(const float4*)&Bs[k][tcol];
            const float4 bv1 = *(const float4*)&Bs[k][tcol + 4];
            const float aa[8] = {av0.x,av0.y,av0.z,av0.w,av1.x,av1.y,av1.z,av1.w};
            const float bb[8] = {bv0.x,bv0.y,bv0.z,bv0.w,bv1.x,bv1.y,bv1.z,bv1.w};
            #pragma unroll
            for (int i = 0; i < 8; i++)
                #pragma unroll
                for (int j = 0; j < 8; j++)
                    acc[i][j] = fmaf(aa[i], bb[j], acc[i][j]);
        }
    }

    const int col = c0 + tcol;
    const float4 bxa = *(const float4*)(bx + col);
    const float4 bxb = *(const float4*)(bx + col + 4);
    #pragma unroll
    for (int i = 0; i < 8; i++) {
        float4 r0, r1;
        r0.x = acc[i][0] + bxa.x; r0.y = acc[i][1] + bxa.y;
        r0.z = acc[i][2] + bxa.z; r0.w = acc[i][3] + bxa.w;
        r1.x = acc[i][4] + bxb.x; r1.y = acc[i][5] + bxb.y;
        r1.z = acc[i][6] + bxb.z; r1.w = acc[i][7] + bxb.w;
        float* dst = gx + (long)(n0 + trow + i) * GXC + col;
        *(float4*)dst = r0;
        *(float4*)(dst + 4) = r1;
    }
}

// ---------- Kernel 2: leaves — pure elementwise (4 nodes/block) -------------
__global__ __launch_bounds__(256) void leaf_kernel(
    const float* __restrict__ gx, const float* __restrict__ bh,
    float* __restrict__ Hb, float* __restrict__ Cb)
{
    const int t = threadIdx.x;
    const float bi = bh[t], bo = bh[512 + t], bu = bh[768 + t];
    #pragma unroll
    for (int s = 0; s < 4; s++) {
        const int node = LEAF_FIRST + blockIdx.x * 4 + s;
        const float* g = gx + (long)node * GXC;
        const float gi = g[t]       + bi;
        const float go = g[512 + t] + bo;
        const float gu = g[768 + t] + bu;
        const float c  = sigf(gi) * tanhf(gu);
        const float h  = sigf(go) * tanhf(c);
        Hb[(long)node * HDIM + t] = h;
        Cb[(long)node * HDIM + t] = c;
    }
}

// ---------- shared device body: one 64x64 level-GEMM tile (pipelined) -------
__device__ __forceinline__ void gemm_body(
    int first, int M, int sec, int c0, int r0,
    const float* __restrict__ Hb, const int* __restrict__ child_idx,
    const float* __restrict__ child_mask, const float* __restrict__ Wh,
    float* __restrict__ D, float (*Xs)[68], float (*Ws)[68])
{
    const int tid  = threadIdx.x;
    const int sr   = tid >> 2;
    const int sk   = (tid & 3) << 2;
    const int trow = (tid >> 4) << 2;
    const int tcol = (tid & 15) << 2;

    const float* Wg;
    if      (sec == 0) Wg = Wh;                  // i
    else if (sec == 1) Wg = Wh + 2 * WH_STRIDE;  // o
    else if (sec == 2) Wg = Wh + 3 * WH_STRIDE;  // u
    else               Wg = Wh + 1 * WH_STRIDE;  // f

    const int  nl    = c0 + sr;
    const bool valid = nl < M;
    int   ci[4];
    float cm[4] = {0.f, 0.f, 0.f, 0.f};
    if (valid) {
        const int n = first + nl;
        if (sec < 3) {
            #pragma unroll
            for (int k = 0; k < 4; k++) {
                ci[k] = child_idx[n * 4 + k];
                cm[k] = child_mask[n * 4 + k];
            }
        } else {
            ci[0] = child_idx[n * 4 + (sec - 3)];
            cm[0] = child_mask[n * 4 + (sec - 3)];
        }
    }
    const long wrow = (long)(r0 + sr) * HDIM;

    float acc[4][4] = {};
    float4 hvr[4], wvr;

    // prefetch chunk 0
    #pragma unroll
    for (int k = 0; k < 4; k++) hvr[k] = make_float4(0.f, 0.f, 0.f, 0.f);
    if (valid) {
        if (sec < 3) {
            #pragma unroll
            for (int k = 0; k < 4; k++)
                if (cm[k] != 0.f)
                    hvr[k] = *(const float4*)(Hb + ci[k] * HDIM + sk);
        } else if (cm[0] != 0.f) {
            hvr[0] = *(const float4*)(Hb + ci[0] * HDIM + sk);
        }
    }
    wvr = *(const float4*)(Wg + wrow + sk);

    for (int k0 = 0; k0 < HDIM; k0 += 16) {
        __syncthreads();
        float4 xv;
        xv.x = hvr[0].x + hvr[1].x + hvr[2].x + hvr[3].x;
        xv.y = hvr[0].y + hvr[1].y + hvr[2].y + hvr[3].y;
        xv.z = hvr[0].z + hvr[1].z + hvr[2].z + hvr[3].z;
        xv.w = hvr[0].w + hvr[1].w + hvr[2].w + hvr[3].w;
        Xs[sk+0][sr] = xv.x; Xs[sk+1][sr] = xv.y; Xs[sk+2][sr] = xv.z; Xs[sk+3][sr] = xv.w;
        Ws[sk+0][sr] = wvr.x; Ws[sk+1][sr] = wvr.y; Ws[sk+2][sr] = wvr.z; Ws[sk+3][sr] = wvr.w;
        __syncthreads();

        const int kn = k0 + 16;
        if (kn < HDIM) {
            #pragma unroll
            for (int k = 0; k < 4; k++) hvr[k] = make_float4(0.f, 0.f, 0.f, 0.f);
            if (valid) {
                if (sec < 3) {
                    #pragma unroll
                    for (int k = 0; k < 4; k++)
                        if (cm[k] != 0.f)
                            hvr[k] = *(const float4*)(Hb + ci[k] * HDIM + kn + sk);
                } else if (cm[0] != 0.f) {
                    hvr[0] = *(const float4*)(Hb + ci[0] * HDIM + kn + sk);
                }
            }
            wvr = *(const float4*)(Wg + wrow + kn + sk);
        }

        #pragma unroll
        for (int k = 0; k < 16; k++) {
            float4 a = *(const float4*)&Ws[k][trow];
            float4 b = *(const float4*)&Xs[k][tcol];
            float avv[4] = {a.x, a.y, a.z, a.w};
            float bvv[4] = {b.x, b.y, b.z, b.w};
            #pragma unroll
            for (int i = 0; i < 4; i++)
                #pragma unroll
                for (int j = 0; j < 4; j++)
                    acc[i][j] = fmaf(avv[i], bvv[j], acc[i][j]);
        }
    }

    #pragma unroll
    for (int j = 0; j < 4; j++) {
        const int col = c0 + tcol + j;
        if (col < M) {
            float4 r;
            r.x = acc[0][j]; r.y = acc[1][j]; r.z = acc[2][j]; r.w = acc[3][j];
            *(float4*)(D + ((long)(sec * M + col)) * HDIM + r0 + trow) = r;
        }
    }
}

// ---------- Kernel 3: big-level GEMM ----------------------------------------
__global__ __launch_bounds__(256) void level_gemm(
    int first, int M, const float* __restrict__ Hb,
    const int* __restrict__ child_idx, const float* __restrict__ child_mask,
    const float* __restrict__ Wh, float* __restrict__ D)
{
    __shared__ __align__(16) float Xs[16][68];
    __shared__ __align__(16) float Ws[16][68];
    gemm_body(first, M, blockIdx.y, blockIdx.x * 64, blockIdx.z * 64,
              Hb, child_idx, child_mask, Wh, D, Xs, Ws);
}

// ---------- Kernel 4: big-level pointwise -----------------------------------
__global__ __launch_bounds__(256) void level_pointwise(
    int first, int M, const float* __restrict__ gx, const float* __restrict__ D,
    const int* __restrict__ child_idx, const float* __restrict__ child_mask,
    const float* __restrict__ bh, float* __restrict__ Hb, float* __restrict__ Cb)
{
    const int nl = blockIdx.x;
    const int n  = first + nl;
    const int t  = threadIdx.x;
    const float di  = D[((long)(0 * M + nl)) * HDIM + t];
    const float dO  = D[((long)(1 * M + nl)) * HDIM + t];
    const float du  = D[((long)(2 * M + nl)) * HDIM + t];
    const float* g = gx + (long)n * GXC;
    const float gi  = g[t]       + bh[t]       + di;
    const float gfb = g[256 + t] + bh[256 + t];
    const float go  = g[512 + t] + bh[512 + t] + dO;
    const float gu  = g[768 + t] + bh[768 + t] + du;

    float c = sigf(gi) * tanhf(gu);
    #pragma unroll
    for (int k = 0; k < 4; k++) {
        const float m = child_mask[n * 4 + k];
        if (m != 0.f) {
            const float df = D[((long)((3 + k) * M + nl)) * HDIM + t];
            const float cc = Cb[(long)child_idx[n * 4 + k] * HDIM + t];
            c = fmaf(sigf(gfb + df), cc, c);
        }
    }
    const float h = sigf(go) * tanhf(c);
    Hb[(long)n * HDIM + t] = h;
    Cb[(long)n * HDIM + t] = c;
}

// ---------- Kernel 5: tail-level GEMM + last-block fused pointwise ----------
// Grid (1,7,4) = 28 blocks, M <= 64. Each block: proven gemm_body, store D,
// __threadfence + atomicAdd. The 28th arrival runs the whole level's
// pointwise in-block (all D visible via fence/atomic release-acquire chain;
// pattern correctness-validated in round 1). Root level also emits out.
__global__ __launch_bounds__(256) void tail_gemm(
    int first, int M, int do_out,
    const float* __restrict__ Hb_in, const int* __restrict__ child_idx,
    const float* __restrict__ child_mask, const float* __restrict__ Wh,
    float* __restrict__ D, const float* __restrict__ gx,
    const float* __restrict__ bh, float* __restrict__ Hb, float* __restrict__ Cb,
    const float* __restrict__ Wout, const float* __restrict__ bout,
    float* __restrict__ out, unsigned* __restrict__ cnt)
{
    __shared__ __align__(16) float Xs[16][68];
    __shared__ __align__(16) float Ws[16][68];
    __shared__ unsigned is_last;
    __shared__ float hroot[HDIM];
    __shared__ float logits[4];

    gemm_body(first, M, blockIdx.y, blockIdx.x * 64, blockIdx.z * 64,
              Hb_in, child_idx, child_mask, Wh, D, Xs, Ws);

    // release D stores, count arrivals
    __threadfence();
    if (threadIdx.x == 0)
        is_last = (atomicAdd(cnt, 1u) == TAIL_NBLK - 1u) ? 1u : 0u;
    __syncthreads();
    if (!is_last) return;
    __threadfence();   // acquire: all 28 blocks' D stores visible

    // ---- fused pointwise for the whole level (M*256 elems) -----------------
    const int t = threadIdx.x;
    for (int idx = t; idx < M * HDIM; idx += 256) {
        const int nl = idx >> 8;
        const int r  = idx & 255;
        const int n  = first + nl;
        const float di  = D[((long)(0 * M + nl)) * HDIM + r];
        const float dO  = D[((long)(1 * M + nl)) * HDIM + r];
        const float du  = D[((long)(2 * M + nl)) * HDIM + r];
        const float* g = gx + (long)n * GXC;
        const float gi  = g[r]       + bh[r]       + di;
        const float gfb = g[256 + r] + bh[256 + r];
        const float go  = g[512 + r] + bh[512 + r] + dO;
        const float gu  = g[768 + r] + bh[768 + r] + du;
        float c = sigf(gi) * tanhf(gu);
        #pragma unroll
        for (int k = 0; k < 4; k++) {
            const float m = child_mask[n * 4 + k];
            if (m != 0.f) {
                const float df = D[((long)((3 + k) * M + nl)) * HDIM + r];
                const float cc = Cb[(long)child_idx[n * 4 + k] * HDIM + r];
                c = fmaf(sigf(gfb + df), cc, c);
            }
        }
        const float h = sigf(go) * tanhf(c);
        Hb[(long)n * HDIM + r] = h;
        Cb[(long)n * HDIM + r] = c;
        if (do_out) hroot[r] = h;   // M==1: idx==t==r, covers all 256
    }

    if (do_out) {
        __syncthreads();
        const int o    = t >> 6;
        const int lane = t & 63;
        float s = 0.f;
        for (int jj = lane; jj < HDIM; jj += 64)
            s = fmaf(Wout[o * HDIM + jj], hroot[jj], s);
        #pragma unroll
        for (int off = 32; off > 0; off >>= 1)
            s += __shfl_down(s, off, 64);
        if (lane == 0) logits[o] = s + bout[o];
        __syncthreads();
        if (t == 0) {
            float m = logits[0];
            #pragma unroll
            for (int i = 1; i < 4; i++) m = fmaxf(m, logits[i]);
            float se = 0.f;
            #pragma unroll
            for (int i = 0; i < 4; i++) se += __expf(logits[i] - m);
            const float lse = m + __logf(se);
            #pragma unroll
            for (int i = 0; i < 4; i++) out[i] = logits[i] - lse;
        }
    }
}

extern "C" void kernel_launch(void* const* d_in, const int* in_sizes, int n_in,
                              void* d_out, int out_size, void* d_ws, size_t ws_size,
                              hipStream_t stream)
{
    const int*   xs         = (const int*)  d_in[0];
    const int*   child_idx  = (const int*)  d_in[1];
    const float* child_mask = (const float*)d_in[2];
    const float* emb        = (const float*)d_in[3];
    const float* Wx         = (const float*)d_in[4];
    const float* bx         = (const float*)d_in[5];
    const float* Wh         = (const float*)d_in[6];
    const float* bh         = (const float*)d_in[7];
    const float* Wout       = (const float*)d_in[8];
    const float* bout       = (const float*)d_in[9];
    float* out = (float*)d_out;

    float* gxb = (float*)d_ws;
    float* Hb  = gxb + (size_t)N_NODES * GXC;
    float* Cb  = Hb  + (size_t)N_NODES * HDIM;
    // D aliases gx leaf rows (dead after leaf_kernel): rows 2048..~3840 max.
    float* Dbuf = gxb + (size_t)LEAF_FIRST * GXC;
    // Tail counters: gx row 8191, cols 256.. (leaf f-cols, never written/read).
    unsigned* cnts = (unsigned*)(gxb + (size_t)(N_NODES - 1) * GXC + 256);

    gx_gemm<<<dim3(8, 64), 256, 0, stream>>>(xs, emb, Wx, bx, gxb, cnts);
    leaf_kernel<<<(N_NODES - LEAF_FIRST) / 4, 256, 0, stream>>>(gxb, bh, Hb, Cb);

    // Big levels: proven pipelined pair.
    const int pfb[3] = {1365, 341, 85};
    const int pcb[3] = { 683, 1024, 256};
    for (int p = 0; p < 3; p++) {
        const int M = pcb[p];
        dim3 grid((M + 63) / 64, 7, 4);
        level_gemm<<<grid, 256, 0, stream>>>(pfb[p], M, Hb, child_idx, child_mask,
                                             Wh, Dbuf);
        level_pointwise<<<M, 256, 0, stream>>>(pfb[p], M, gxb, Dbuf, child_idx,
                                               child_mask, bh, Hb, Cb);
    }

    // Tail levels: single dispatch each (last-block fused pointwise).
    const int pft[4] = {21, 5, 1, 0};
    const int pct[4] = {64, 16, 4, 1};
    for (int p = 0; p < 4; p++) {
        dim3 grid(1, 7, 4);   // TAIL_NBLK = 28
        tail_gemm<<<grid, 256, 0, stream>>>(pft[p], pct[p], (p == 3) ? 1 : 0,
                                            Hb, child_idx, child_mask, Wh, Dbuf,
                                            gxb, bh, Hb, Cb, Wout, bout, out,
                                            cnts + p);
    }
}

// Round 8
// 307.793 us; speedup vs baseline: 1.8218x; 1.8218x over previous
//
#include <hip/hip_runtime.h>

// ChildSumTreeLSTM on a static 4-ary heap tree.
// N=8192, H=256, D=300, K=4, OUT=4. Leaves = 2048..8191. Internal 0..2047 in 7 levels.
// Workspace: gx [8192][1024] f32, Hb [8192][256] f32, Cb [8192][256] f32.
// D (big-level scratch, <=7.3MB) aliases gx rows 2048.. (dead after leaf_kernel).
//
// Structure (13 dispatches):
//   1. gx_gemm     — 128x128 tiles (proven round 7), pipelined, XCD-swizzled
//                    (emb L2-resident, FETCH ~11MB), dead leaf-f tiles skipped.
//   2. leaf_kernel — 4 nodes/block.
//   3-8. big levels M=683,1024,256: level_gemm (64x64, pipelined) +
//        level_pointwise (round-5-proven pair).
//   9-11. tail levels M=64,16,4: tail_fused — block = (node, 64-row block),
//        grid (M,4); W read directly from L2 (256KB/block), X staged in LDS
//        with ONE sync; GEMV + pointwise in-block. No fences, no chunk loop.
//   12-13. root M=1: level_gemm + level_pointwise(do_out) — out needs full h.
// Hard rules (rounds 1-7): NO device-scope fences/atomics in-kernel (round 7:
// one threadfence+atomic per block => ~200us/dispatch; round 1: grid barrier
// ~170us/sync). No chunked-LDS fused levels (rounds 4/6). Per-block W <=256KB
// with >=16 blocks (rounds 2/3). Launch tax ~14us/dispatch.

#define N_NODES 8192
#define HDIM 256
#define DDIM 300
#define GXC 1024
#define LEAF_FIRST 2048
#define WH_STRIDE 65536   // 256*256
#define XI(k) ((k) + (((k) >> 6) << 2))   // padded X index: quarter j -> +4j banks

__device__ __forceinline__ float sigf(float x) { return 1.0f / (1.0f + __expf(-x)); }

// ---------- Kernel 1: gx[n][c] = emb[xs[n]] · Wx[c] + bx[c]  (128x128 tile) --
__global__ __launch_bounds__(256) void gx_gemm(
    const int* __restrict__ xs, const float* __restrict__ emb,
    const float* __restrict__ Wx, const float* __restrict__ bx,
    float* __restrict__ gx)
{
    // XCD remap: grid (8,64) -> lid 0..511; XCD = lid&7 owns 8 row-tiles with
    // all 8 col-tiles -> each XCD HBM-fetches its 1.2MB of emb rows once.
    const int lid  = blockIdx.x + blockIdx.y * gridDim.x;
    const int rowt = (lid & 7) * 8 + ((lid >> 3) & 7);   // 0..63
    const int colt = lid >> 6;                           // 0..7
    const int n0 = rowt * 128;
    const int c0 = colt * 128;
    // Leaf rows' f-gate cols (256..511 = col-tiles 2,3) never read: skip.
    if (n0 >= LEAF_FIRST && (colt == 2 || colt == 3)) return;

    __shared__ __align__(16) float As[16][132];
    __shared__ __align__(16) float Bs[16][132];
    const int tid  = threadIdx.x;
    const int sr   = tid >> 1;           // staging row 0..127
    const int sk8  = (tid & 1) << 3;     // staging k-offset 0/8
    const int trow = (tid >> 4) << 3;    // 0..120
    const int tcol = (tid & 15) << 3;    // 0..120

    const long arow = (long)xs[n0 + sr] * DDIM;
    const long brow = (long)(c0 + sr) * DDIM;

    float acc[8][8] = {};

    // prefetch chunk 0 (fully in-range: 16 <= 300)
    float4 a0 = *(const float4*)(emb + arow + sk8);
    float4 a1 = *(const float4*)(emb + arow + sk8 + 4);
    float4 b0 = *(const float4*)(Wx  + brow + sk8);
    float4 b1 = *(const float4*)(Wx  + brow + sk8 + 4);

    for (int k0 = 0; k0 < DDIM; k0 += 16) {
        __syncthreads();
        As[sk8+0][sr] = a0.x; As[sk8+1][sr] = a0.y; As[sk8+2][sr] = a0.z; As[sk8+3][sr] = a0.w;
        As[sk8+4][sr] = a1.x; As[sk8+5][sr] = a1.y; As[sk8+6][sr] = a1.z; As[sk8+7][sr] = a1.w;
        Bs[sk8+0][sr] = b0.x; Bs[sk8+1][sr] = b0.y; Bs[sk8+2][sr] = b0.z; Bs[sk8+3][sr] = b0.w;
        Bs[sk8+4][sr] = b1.x; Bs[sk8+5][sr] = b1.y; Bs[sk8+6][sr] = b1.z; Bs[sk8+7][sr] = b1.w;
        __syncthreads();

        // prefetch next chunk (overlaps compute); zero-pad past DDIM
        const int kn = k0 + 16;
        a0 = make_float4(0.f,0.f,0.f,0.f); a1 = a0; b0 = a0; b1 = a0;
        if (kn < DDIM) {
            if (kn + sk8 < DDIM) {
                a0 = *(const float4*)(emb + arow + kn + sk8);
                b0 = *(const float4*)(Wx  + brow + kn + sk8);
            }
            if (kn + sk8 + 4 < DDIM) {
                a1 = *(const float4*)(emb + arow + kn + sk8 + 4);
                b1 = *(const float4*)(Wx  + brow + kn + sk8 + 4);
            }
        }

        #pragma unroll
        for (int k = 0; k < 16; k++) {
            const float4 av0 = *(const float4*)&As[k][trow];
            const float4 av1 = *(const float4*)&As[k][trow + 4];
            const float4 bv0 = *(const float4*)&Bs[k][tcol];
            const float4 bv1 = *(const float4*)&Bs[k][tcol + 4];
            const float aa[8] = {av0.x,av0.y,av0.z,av0.w,av1.x,av1.y,av1.z,av1.w};
            const float bb[8] = {bv0.x,bv0.y,bv0.z,bv0.w,bv1.x,bv1.y,bv1.z,bv1.w};
            #pragma unroll
            for (int i = 0; i < 8; i++)
                #pragma unroll
                for (int j = 0; j < 8; j++)
                    acc[i][j] = fmaf(aa[i], bb[j], acc[i][j]);
        }
    }

    const int col = c0 + tcol;
    const float4 bxa = *(const float4*)(bx + col);
    const float4 bxb = *(const float4*)(bx + col + 4);
    #pragma unroll
    for (int i = 0; i < 8; i++) {
        float4 r0, r1;
        r0.x = acc[i][0] + bxa.x; r0.y = acc[i][1] + bxa.y;
        r0.z = acc[i][2] + bxa.z; r0.w = acc[i][3] + bxa.w;
        r1.x = acc[i][4] + bxb.x; r1.y = acc[i][5] + bxb.y;
        r1.z = acc[i][6] + bxb.z; r1.w = acc[i][7] + bxb.w;
        float* dst = gx + (long)(n0 + trow + i) * GXC + col;
        *(float4*)dst = r0;
        *(float4*)(dst + 4) = r1;
    }
}

// ---------- Kernel 2: leaves — pure elementwise (4 nodes/block) -------------
__global__ __launch_bounds__(256) void leaf_kernel(
    const float* __restrict__ gx, const float* __restrict__ bh,
    float* __restrict__ Hb, float* __restrict__ Cb)
{
    const int t = threadIdx.x;
    const float bi = bh[t], bo = bh[512 + t], bu = bh[768 + t];
    #pragma unroll
    for (int s = 0; s < 4; s++) {
        const int node = LEAF_FIRST + blockIdx.x * 4 + s;
        const float* g = gx + (long)node * GXC;
        const float gi = g[t]       + bi;
        const float go = g[512 + t] + bo;
        const float gu = g[768 + t] + bu;
        const float c  = sigf(gi) * tanhf(gu);
        const float h  = sigf(go) * tanhf(c);
        Hb[(long)node * HDIM + t] = h;
        Cb[(long)node * HDIM + t] = c;
    }
}

// ---------- Kernel 3: big-level GEMM (64x64, pipelined; round-5-proven) -----
__global__ __launch_bounds__(256) void level_gemm(
    int first, int M, const float* __restrict__ Hb,
    const int* __restrict__ child_idx, const float* __restrict__ child_mask,
    const float* __restrict__ Wh, float* __restrict__ D)
{
    __shared__ __align__(16) float Xs[16][68];
    __shared__ __align__(16) float Ws[16][68];
    const int tid  = threadIdx.x;
    const int sec  = blockIdx.y;
    const int c0   = blockIdx.x * 64;
    const int r0   = blockIdx.z * 64;
    const int sr   = tid >> 2;
    const int sk   = (tid & 3) << 2;
    const int trow = (tid >> 4) << 2;
    const int tcol = (tid & 15) << 2;

    const float* Wg;
    if      (sec == 0) Wg = Wh;                  // i
    else if (sec == 1) Wg = Wh + 2 * WH_STRIDE;  // o
    else if (sec == 2) Wg = Wh + 3 * WH_STRIDE;  // u
    else               Wg = Wh + 1 * WH_STRIDE;  // f

    const int  nl    = c0 + sr;
    const bool valid = nl < M;
    int   ci[4];
    float cm[4] = {0.f, 0.f, 0.f, 0.f};
    if (valid) {
        const int n = first + nl;
        if (sec < 3) {
            #pragma unroll
            for (int k = 0; k < 4; k++) {
                ci[k] = child_idx[n * 4 + k];
                cm[k] = child_mask[n * 4 + k];
            }
        } else {
            ci[0] = child_idx[n * 4 + (sec - 3)];
            cm[0] = child_mask[n * 4 + (sec - 3)];
        }
    }
    const long wrow = (long)(r0 + sr) * HDIM;

    float acc[4][4] = {};
    float4 hvr[4], wvr;

    // prefetch chunk 0
    #pragma unroll
    for (int k = 0; k < 4; k++) hvr[k] = make_float4(0.f, 0.f, 0.f, 0.f);
    if (valid) {
        if (sec < 3) {
            #pragma unroll
            for (int k = 0; k < 4; k++)
                if (cm[k] != 0.f)
                    hvr[k] = *(const float4*)(Hb + ci[k] * HDIM + sk);
        } else if (cm[0] != 0.f) {
            hvr[0] = *(const float4*)(Hb + ci[0] * HDIM + sk);
        }
    }
    wvr = *(const float4*)(Wg + wrow + sk);

    for (int k0 = 0; k0 < HDIM; k0 += 16) {
        __syncthreads();
        float4 xv;
        xv.x = hvr[0].x + hvr[1].x + hvr[2].x + hvr[3].x;
        xv.y = hvr[0].y + hvr[1].y + hvr[2].y + hvr[3].y;
        xv.z = hvr[0].z + hvr[1].z + hvr[2].z + hvr[3].z;
        xv.w = hvr[0].w + hvr[1].w + hvr[2].w + hvr[3].w;
        Xs[sk+0][sr] = xv.x; Xs[sk+1][sr] = xv.y; Xs[sk+2][sr] = xv.z; Xs[sk+3][sr] = xv.w;
        Ws[sk+0][sr] = wvr.x; Ws[sk+1][sr] = wvr.y; Ws[sk+2][sr] = wvr.z; Ws[sk+3][sr] = wvr.w;
        __syncthreads();

        const int kn = k0 + 16;
        if (kn < HDIM) {
            #pragma unroll
            for (int k = 0; k < 4; k++) hvr[k] = make_float4(0.f, 0.f, 0.f, 0.f);
            if (valid) {
                if (sec < 3) {
                    #pragma unroll
                    for (int k = 0; k < 4; k++)
                        if (cm[k] != 0.f)
                            hvr[k] = *(const float4*)(Hb + ci[k] * HDIM + kn + sk);
                } else if (cm[0] != 0.f) {
                    hvr[0] = *(const float4*)(Hb + ci[0] * HDIM + kn + sk);
                }
            }
            wvr = *(const float4*)(Wg + wrow + kn + sk);
        }

        #pragma unroll
        for (int k = 0; k < 16; k++) {
            float4 a = *(const float4*)&Ws[k][trow];
            float4 b = *(const float4*)&Xs[k][tcol];
            float avv[4] = {a.x, a.y, a.z, a.w};
            float bvv[4] = {b.x, b.y, b.z, b.w};
            #pragma unroll
            for (int i = 0; i < 4; i++)
                #pragma unroll
                for (int j = 0; j < 4; j++)
                    acc[i][j] = fmaf(avv[i], bvv[j], acc[i][j]);
        }
    }

    #pragma unroll
    for (int j = 0; j < 4; j++) {
        const int col = c0 + tcol + j;
        if (col < M) {
            float4 r;
            r.x = acc[0][j]; r.y = acc[1][j]; r.z = acc[2][j]; r.w = acc[3][j];
            *(float4*)(D + ((long)(sec * M + col)) * HDIM + r0 + trow) = r;
        }
    }
}

// ---------- Kernel 4: level pointwise (do_out folds logits on root) ---------
__global__ __launch_bounds__(256) void level_pointwise(
    int first, int M, int do_out,
    const float* __restrict__ gx, const float* __restrict__ D,
    const int* __restrict__ child_idx, const float* __restrict__ child_mask,
    const float* __restrict__ bh, float* __restrict__ Hb, float* __restrict__ Cb,
    const float* __restrict__ Wout, const float* __restrict__ bout,
    float* __restrict__ out)
{
    __shared__ float hroot[HDIM];
    __shared__ float logits[4];
    const int nl = blockIdx.x;
    const int n  = first + nl;
    const int t  = threadIdx.x;
    const float di  = D[((long)(0 * M + nl)) * HDIM + t];
    const float dO  = D[((long)(1 * M + nl)) * HDIM + t];
    const float du  = D[((long)(2 * M + nl)) * HDIM + t];
    const float* g = gx + (long)n * GXC;
    const float gi  = g[t]       + bh[t]       + di;
    const float gfb = g[256 + t] + bh[256 + t];
    const float go  = g[512 + t] + bh[512 + t] + dO;
    const float gu  = g[768 + t] + bh[768 + t] + du;

    float c = sigf(gi) * tanhf(gu);
    #pragma unroll
    for (int k = 0; k < 4; k++) {
        const float m = child_mask[n * 4 + k];
        if (m != 0.f) {
            const float df = D[((long)((3 + k) * M + nl)) * HDIM + t];
            const float cc = Cb[(long)child_idx[n * 4 + k] * HDIM + t];
            c = fmaf(sigf(gfb + df), cc, c);
        }
    }
    const float h = sigf(go) * tanhf(c);
    Hb[(long)n * HDIM + t] = h;
    Cb[(long)n * HDIM + t] = c;

    if (do_out) {
        hroot[t] = h;                       // n==0, single block
        __syncthreads();
        const int o    = t >> 6;
        const int lane = t & 63;
        float s = 0.f;
        for (int jj = lane; jj < HDIM; jj += 64)
            s = fmaf(Wout[o * HDIM + jj], hroot[jj], s);
        #pragma unroll
        for (int off = 32; off > 0; off >>= 1)
            s += __shfl_down(s, off, 64);
        if (lane == 0) logits[o] = s + bout[o];
        __syncthreads();
        if (t == 0) {
            float m = logits[0];
            #pragma unroll
            for (int i = 1; i < 4; i++) m = fmaxf(m, logits[i]);
            float se = 0.f;
            #pragma unroll
            for (int i = 0; i < 4; i++) se += __expf(logits[i] - m);
            const float lse = m + __logf(se);
            #pragma unroll
            for (int i = 0; i < 4; i++) out[i] = logits[i] - lse;
        }
    }
}

// ---------- Kernel 5: tail-fused level (M=64/16/4) --------------------------
// Grid (M, 4): block = (node nl, 64-row block rb). 256 threads.
// Stage node's children h in LDS (one sync), GEMV all 7 sections for rows
// rb*64..+63 with W rows read straight from L2 (256KB/block), quad-reduce,
// pointwise those rows in-block. No scratch D, no fences, no chunk loop.
__global__ __launch_bounds__(256) void tail_fused(
    int first, int M,
    const float* __restrict__ gx, const int* __restrict__ child_idx,
    const float* __restrict__ child_mask, const float* __restrict__ Wh,
    const float* __restrict__ bh, float* __restrict__ Hb, float* __restrict__ Cb)
{
    __shared__ __align__(16) float Xc[4][272];   // children h (masked), padded
    __shared__ __align__(16) float Xh[272];      // child-h sum, padded
    __shared__ float Ds[7][64];                  // section results for this rb

    const int t  = threadIdx.x;
    const int nl = blockIdx.x;
    const int rb = blockIdx.y;
    const int n  = first + nl;

    // ---- stage children h (masked): thread -> (child t>>6, 4 elems) --------
    {
        const int ch = t >> 6;
        const int e4 = (t & 63) << 2;
        const int cidx = child_idx[n * 4 + ch];
        const float m  = child_mask[n * 4 + ch];
        float4 v = make_float4(0.f, 0.f, 0.f, 0.f);
        if (m != 0.f) v = *(const float4*)(Hb + (long)cidx * HDIM + e4);
        *(float4*)&Xc[ch][XI(e4)] = v;
    }
    __syncthreads();
    {
        const int k = t;   // 256 threads, 256 elems
        Xh[XI(k)] = Xc[0][XI(k)] + Xc[1][XI(k)] + Xc[2][XI(k)] + Xc[3][XI(k)];
    }
    __syncthreads();

    // ---- GEMV: thread (q = row-in-block, j = k-quarter) ---------------------
    const int q = t >> 2, j = t & 3;
    const int row = rb * 64 + q;
    const float* Wi = Wh + 0 * WH_STRIDE + (long)row * HDIM;   // gate order i,f,o,u
    const float* Wf = Wh + 1 * WH_STRIDE + (long)row * HDIM;
    const float* Wo = Wh + 2 * WH_STRIDE + (long)row * HDIM;
    const float* Wu = Wh + 3 * WH_STRIDE + (long)row * HDIM;

    float a[7] = {};
    #pragma unroll 4
    for (int kk = j * 64; kk < j * 64 + 64; kk += 4) {
        const float4 wi = *(const float4*)(Wi + kk);
        const float4 wo = *(const float4*)(Wo + kk);
        const float4 wu = *(const float4*)(Wu + kk);
        const float4 wf = *(const float4*)(Wf + kk);
        const float4 hs = *(const float4*)&Xh[XI(kk)];
        a[0] += wi.x*hs.x + wi.y*hs.y + wi.z*hs.z + wi.w*hs.w;
        a[1] += wo.x*hs.x + wo.y*hs.y + wo.z*hs.z + wo.w*hs.w;
        a[2] += wu.x*hs.x + wu.y*hs.y + wu.z*hs.z + wu.w*hs.w;
        #pragma unroll
        for (int ch = 0; ch < 4; ch++) {
            const float4 cv = *(const float4*)&Xc[ch][XI(kk)];
            a[3 + ch] += wf.x*cv.x + wf.y*cv.y + wf.z*cv.z + wf.w*cv.w;
        }
    }
    #pragma unroll
    for (int s = 0; s < 7; s++) {
        float v = a[s];
        v += __shfl_xor(v, 1, 64);
        v += __shfl_xor(v, 2, 64);
        if (j == 0) Ds[s][q] = v;
    }
    __syncthreads();

    // ---- pointwise for rows rb*64..+63 (threads 0..63) ----------------------
    if (t < 64) {
        const int r = rb * 64 + t;
        const float* g = gx + (long)n * GXC;
        const float gi  = g[r]       + bh[r]       + Ds[0][t];
        const float gfb = g[256 + r] + bh[256 + r];
        const float go  = g[512 + r] + bh[512 + r] + Ds[1][t];
        const float gu  = g[768 + r] + bh[768 + r] + Ds[2][t];
        float c = sigf(gi) * tanhf(gu);
        #pragma unroll
        for (int ch = 0; ch < 4; ch++) {
            const float m = child_mask[n * 4 + ch];
            if (m != 0.f) {
                const float cc = Cb[(long)child_idx[n * 4 + ch] * HDIM + r];
                c = fmaf(sigf(gfb + Ds[3 + ch][t]), cc, c);
            }
        }
        const float h = sigf(go) * tanhf(c);
        Hb[(long)n * HDIM + r] = h;
        Cb[(long)n * HDIM + r] = c;
    }
}

extern "C" void kernel_launch(void* const* d_in, const int* in_sizes, int n_in,
                              void* d_out, int out_size, void* d_ws, size_t ws_size,
                              hipStream_t stream)
{
    const int*   xs         = (const int*)  d_in[0];
    const int*   child_idx  = (const int*)  d_in[1];
    const float* child_mask = (const float*)d_in[2];
    const float* emb        = (const float*)d_in[3];
    const float* Wx         = (const float*)d_in[4];
    const float* bx         = (const float*)d_in[5];
    const float* Wh         = (const float*)d_in[6];
    const float* bh         = (const float*)d_in[7];
    const float* Wout       = (const float*)d_in[8];
    const float* bout       = (const float*)d_in[9];
    float* out = (float*)d_out;

    float* gxb = (float*)d_ws;
    float* Hb  = gxb + (size_t)N_NODES * GXC;
    float* Cb  = Hb  + (size_t)N_NODES * HDIM;
    // D aliases gx leaf rows (dead after leaf_kernel): rows 2048..~3840 max.
    float* Dbuf = gxb + (size_t)LEAF_FIRST * GXC;

    gx_gemm<<<dim3(8, 64), 256, 0, stream>>>(xs, emb, Wx, bx, gxb);
    leaf_kernel<<<(N_NODES - LEAF_FIRST) / 4, 256, 0, stream>>>(gxb, bh, Hb, Cb);

    // Big levels: proven pipelined pair.
    const int pfb[3] = {1365, 341, 85};
    const int pcb[3] = { 683, 1024, 256};
    for (int p = 0; p < 3; p++) {
        const int M = pcb[p];
        dim3 grid((M + 63) / 64, 7, 4);
        level_gemm<<<grid, 256, 0, stream>>>(pfb[p], M, Hb, child_idx, child_mask,
                                             Wh, Dbuf);
        level_pointwise<<<M, 256, 0, stream>>>(pfb[p], M, 0, gxb, Dbuf, child_idx,
                                               child_mask, bh, Hb, Cb,
                                               Wout, bout, out);
    }

    // Tail levels M=64,16,4: single fused dispatch each.
    const int pft[3] = {21, 5, 1};
    const int pct[3] = {64, 16, 4};
    for (int p = 0; p < 3; p++) {
        dim3 grid(pct[p], 4);
        tail_fused<<<grid, 256, 0, stream>>>(pft[p], pct[p], gxb, child_idx,
                                             child_mask, Wh, bh, Hb, Cb);
    }

    // Root level M=1: pair (out needs the full h vector in one block).
    {
        dim3 grid(1, 7, 4);
        level_gemm<<<grid, 256, 0, stream>>>(0, 1, Hb, child_idx, child_mask,
                                             Wh, Dbuf);
        level_pointwise<<<1, 256, 0, stream>>>(0, 1, 1, gxb, Dbuf, child_idx,
                                               child_mask, bh, Hb, Cb,
                                               Wout, bout, out);
    }
}